// Round 5
// baseline (925.551 us; speedup 1.0000x reference)
//
#include <hip/hip_runtime.h>
#include <cstdint>
#include <cstddef>

// ---------------------------------------------------------------------------
// MultiHeadSelfAttention: x(64,64,4096) fp32; W q/k/v/o (4096,4096); quirky RoPE
// Pipeline: fused cast->f16 | GEMM qkv (M4096,N12288,K4096) | fused rope+attn
//           per (b,h) | GEMM out-proj -> fp32 d_out
// R7: (a) 32x32x16 f16 MFMA (µbench 2382 vs 2075 TF, 4x fewer instrs);
//     (b) single-barrier phases (4/tile) with reads for phase p+1 issued in
//         p's post-MFMA window, pinned by sched_barrier(0) BEFORE each
//         s_barrier (R3/R4/R6 all measured identical 42-45% MfmaUtil ->
//         compiler sinks plain LDS loads across raw s_barrier to their uses;
//         the pre-barrier sched_barrier is the only motion fence).
//     Phase map (wave tile 128x64 = 4 m-frags x 2 n-frags of 32x32, BK=64 =
//     4 k-steps): p1=(m01,n0) reads af01+bq0 at top (post-barrier, forced by
//     prev p4 vmcnt) + bq1 post; p2=(m01,n1) reads af23 post; p3=(m23,n0);
//     p4=(m23,n1) + STAGE Bh1(t+2) + vmcnt(6) + barrier.
//     STAGE stagger (WAR/RAW audited): p1: Ah1(t+1)->nbuf; p2: Ah0(t+2)->cur;
//     p3: Bh0(t+2)->cur; p4: Bh1(t+2)->cur. vmcnt(6) leaves exactly
//     {Ah0,Bh0,Bh1}(t+2) in flight; barrier after vmcnt makes all waves'
//     staging of tile t+1 visible before any wave reads it at p1(t+1)-top.
// ---------------------------------------------------------------------------

typedef _Float16 half8 __attribute__((ext_vector_type(8)));
typedef float floatx4 __attribute__((ext_vector_type(4)));
typedef float floatx16 __attribute__((ext_vector_type(16)));

#define NELT_W 16777216u   // 4096*4096
#define NEG_LOG2_10000_OVER_2048 (-0.0064881408103278559f)

// async global->LDS, 16 bytes per lane
__device__ __forceinline__ void gl_lds16(const void* g, void* l) {
    __builtin_amdgcn_global_load_lds(
        (const __attribute__((address_space(1))) void*)(void*)g,
        (__attribute__((address_space(3))) void*)l,
        16, 0, 0);
}

// ---------------------------------------------------------------------------
// fused fp32 -> f16 cast of all 5 tensors: blockIdx.y selects tensor
// ---------------------------------------------------------------------------
__global__ __launch_bounds__(256) void cast5_kernel(
    const float* __restrict__ x,  const float* __restrict__ wq,
    const float* __restrict__ wk, const float* __restrict__ wv,
    const float* __restrict__ wo,
    _Float16* __restrict__ xh, _Float16* __restrict__ wcat,
    _Float16* __restrict__ woh)
{
    const float* s;
    _Float16* d;
    switch (blockIdx.y) {
        case 0:  s = x;  d = xh;                 break;
        case 1:  s = wq; d = wcat;               break;
        case 2:  s = wk; d = wcat + NELT_W;      break;
        case 3:  s = wv; d = wcat + 2 * NELT_W;  break;
        default: s = wo; d = woh;                break;
    }
    int i0 = (blockIdx.x * 256 + threadIdx.x) * 8;
    int stride = gridDim.x * 256 * 8;
    for (int i = i0; i < (int)NELT_W; i += stride) {
        const float4 a = *(const float4*)(s + i);
        const float4 b = *(const float4*)(s + i + 4);
        half8 h;
        h[0] = (_Float16)a.x; h[1] = (_Float16)a.y;
        h[2] = (_Float16)a.z; h[3] = (_Float16)a.w;
        h[4] = (_Float16)b.x; h[5] = (_Float16)b.y;
        h[6] = (_Float16)b.z; h[7] = (_Float16)b.w;
        *(half8*)(d + i) = h;
    }
}

__global__ __launch_bounds__(256) void biascat_kernel(
    const float* __restrict__ bq, const float* __restrict__ bk,
    const float* __restrict__ bv, float* __restrict__ out)
{
    int i = blockIdx.x * 256 + threadIdx.x;
    if (i < 4096) {
        out[i]        = bq[i];
        out[4096 + i] = bk[i];
        out[8192 + i] = bv[i];
    }
}

// ---------------------------------------------------------------------------
// NT GEMM, 256x256 tile, BK=64, 32x32x16 MFMA, single-barrier 4-phase.
// C[m,n] = sum_k A[m,k]*B[n,k] + bias[n]; A: MxK f16 rm, B: NxK f16 rm.
// Requires M%256==0, N%256==0, K%64==0, K/64 even >=4, grid%8==0.
// ---------------------------------------------------------------------------

#define BAR()   __builtin_amdgcn_s_barrier()
#define SB0()   __builtin_amdgcn_sched_barrier(0)
#define SETP1() __builtin_amdgcn_s_setprio(1)
#define SETP0() __builtin_amdgcn_s_setprio(0)

// stage one half-tile (128 rows x 64 cols f16) = 2 gl_lds16 per thread
#define STAGE(gb_, lb_, kt_, half_) do {                                      \
    const int R0_ = (half_) << 7;                                             \
    gl_lds16((gb_) + (size_t)R0_ * K + (kt_), (lb_) + R0_ * 64);              \
    gl_lds16((gb_) + (size_t)(R0_ + 64) * K + (kt_), (lb_) + (R0_ + 64) * 64);\
} while (0)

// A fragments for m-frag pair of half ha_: af[mf][ks], row = ha*128+wg2+mf*32+l31
#define LDA32(bo_, ha_) do {                                                  \
    const _Float16* pa_ = As + (bo_) +                                        \
        (size_t)((((ha_) << 7) + wg2 + l31) * 64);                            \
    _Pragma("unroll") for (int ks_ = 0; ks_ < 4; ++ks_)                       \
    _Pragma("unroll") for (int mf_ = 0; mf_ < 2; ++mf_)                       \
        af[mf_][ks_] = *(const half8*)(pa_ + mf_ * 2048 + swzk[ks_]);         \
} while (0)

// B fragments for half hb_ into dst: col(row of Bs) = hb*128+wn2+l31
#define LDB32(bo_, hb_, dst_) do {                                            \
    const _Float16* pb_ = Bs + (bo_) +                                        \
        (size_t)((((hb_) << 7) + wn2 + l31) * 64);                            \
    _Pragma("unroll") for (int ks_ = 0; ks_ < 4; ++ks_)                       \
        dst_[ks_] = *(const half8*)(pb_ + swzk[ks_]);                         \
} while (0)

// 8 MFMAs (2 m-frags x 4 k-steps) for quadrant (mq, nq)
#define MFMA8(mq_, nq_, bqv_) do {                                            \
    _Pragma("unroll") for (int ks_ = 0; ks_ < 4; ++ks_)                       \
    _Pragma("unroll") for (int mf_ = 0; mf_ < 2; ++mf_)                       \
        acc[(mq_) * 2 + mf_][nq_] = __builtin_amdgcn_mfma_f32_32x32x16_f16(   \
            af[mf_][ks_], bqv_[ks_], acc[(mq_) * 2 + mf_][nq_], 0, 0, 0);     \
} while (0)

// one K-tile = 4 phases, one barrier each; uses scope vars t, bufo, nbufo
#define TILE() do {                                                           \
    const int kt1_ = (t + 1) << 6;                                            \
    const int kt2_ = (t + 2) << 6;                                            \
    const bool s1_ = (t + 1 < NT);                                            \
    const bool s2_ = (t + 2 < NT);                                            \
    /* p1: (m01,n0). reads af01(t)+bq0(t) at top; bq1(t) post; stage Ah1 */   \
    LDA32(bufo, 0);                                                           \
    LDB32(bufo, 0, bq0);                                                      \
    SETP1(); MFMA8(0, 0, bq0); SETP0();                                       \
    LDB32(bufo, 1, bq1);                                                      \
    if (s1_) STAGE(Ab, AsT + nbufo, kt1_, 1);                                 \
    SB0(); BAR();                                                             \
    /* p2: (m01,n1). af23(t) post (for p3); stage Ah0(t+2)->cur */            \
    SETP1(); MFMA8(0, 1, bq1); SETP0();                                       \
    LDA32(bufo, 1);                                                           \
    if (s2_) STAGE(Ab, AsT + bufo, kt2_, 0);                                  \
    SB0(); BAR();                                                             \
    /* p3: (m23,n0). stage Bh0(t+2)->cur */                                   \
    SETP1(); MFMA8(1, 0, bq0); SETP0();                                       \
    if (s2_) STAGE(Bb, BsT + bufo, kt2_, 0);                                  \
    SB0(); BAR();                                                             \
    /* p4: (m23,n1). stage Bh1(t+2)->cur; counted vmcnt; buffer switch */     \
    SETP1(); MFMA8(1, 1, bq1); SETP0();                                       \
    if (s2_) STAGE(Bb, BsT + bufo, kt2_, 1);                                  \
    if (t < NT - 2) asm volatile("s_waitcnt vmcnt(6)" ::: "memory");          \
    else            asm volatile("s_waitcnt vmcnt(0)" ::: "memory");          \
    SB0(); BAR();                                                             \
} while (0)

template <int OUT_F16>
__global__ __launch_bounds__(512, 2) void gemm_nt_256(
    const _Float16* __restrict__ A, const _Float16* __restrict__ B,
    const float* __restrict__ bias, void* __restrict__ Cout,
    int M, int N, int K)
{
    __shared__ __align__(16) _Float16 As[2 * 256 * 64];   // 64 KiB
    __shared__ __align__(16) _Float16 Bs[2 * 256 * 64];   // 64 KiB

    const int tid = threadIdx.x;
    // XCD-bijective block swizzle (grid multiple of 8)
    const int nwg  = gridDim.x;
    const int swz  = (blockIdx.x & 7) * (nwg >> 3) + (blockIdx.x >> 3);
    const int gn   = N >> 8;
    const int row0 = (swz / gn) << 8;
    const int col0 = (swz % gn) << 8;

    const int wave = tid >> 6;
    const int lane = tid & 63;
    const int wg2 = (wave >> 2) << 6;   // 0 or 64: row offset within 128-half
    const int wn2 = (wave & 3) << 5;    // 0,32,64,96: col offset within 128-half
    const int l31 = lane & 31;
    const int hi  = lane >> 5;

    // swizzled chunk offsets (f16 units): logical chunk = ks*2 + hi,
    // phys = chunk ^ (row&7); fragment rows == l31 (mod 8) by construction.
    int swzk[4];
#pragma unroll
    for (int ks = 0; ks < 4; ++ks)
        swzk[ks] = (((ks * 2 + hi) ^ (lane & 7)) << 3);

    // staging: thread t -> row tid>>3, phys chunk tid&7; fetch logical chunk
    // (tid&7)^(row&7) so the ds_read-side swizzle finds the right data.
    const int srow = tid >> 3;
    const int scol = ((tid & 7) ^ (srow & 7)) << 3;
    const _Float16* Ab = A + (size_t)(row0 + srow) * K + scol;
    const _Float16* Bb = B + (size_t)(col0 + srow) * K + scol;
    _Float16* AsT = As + tid * 8;
    _Float16* BsT = Bs + tid * 8;

    floatx16 acc[4][2];
#pragma unroll
    for (int i = 0; i < 4; i++)
#pragma unroll
        for (int j = 0; j < 2; j++)
#pragma unroll
            for (int e = 0; e < 16; e++) acc[i][j][e] = 0.f;

    half8 af[2][4], bq0[4], bq1[4];

    const int NT = K >> 6;

    // prologue: tile0 (4 half-tiles) -> buf0; Ah0,Bh0,Bh1 of tile1 -> buf1.
    // vmcnt(6) forces tile0's 8 loads, leaves tile1's 3 half-tiles in flight
    // (steady-state invariant; Ah1(1) is staged at p1 of tile0).
    STAGE(Ab, AsT, 0, 0);
    STAGE(Ab, AsT, 0, 1);
    STAGE(Bb, BsT, 0, 0);
    STAGE(Bb, BsT, 0, 1);
    STAGE(Ab, AsT + 16384, 64, 0);
    STAGE(Bb, BsT + 16384, 64, 0);
    STAGE(Bb, BsT + 16384, 64, 1);
    asm volatile("s_waitcnt vmcnt(6)" ::: "memory");
    SB0();
    BAR();

    for (int tt = 0; tt < NT; tt += 2) {
        { const int t = tt;     const int bufo = 0;     const int nbufo = 16384; TILE(); }
        { const int t = tt + 1; const int bufo = 16384; const int nbufo = 0;     TILE(); }
    }

    // epilogue: 32x32 C/D layout col=lane&31, row=(reg&3)+8*(reg>>2)+4*(lane>>5)
    // frag (mq,nf): rows row0+(mq>>1)*128+wg2+(mq&1)*32+rif, col col0+nf*128+wn2+l31
    const int crow = row0 + wg2 + (hi << 2);
    const int ccol = col0 + wn2 + l31;
#pragma unroll
    for (int mq = 0; mq < 4; ++mq) {
        const int rbase = crow + ((mq >> 1) << 7) + ((mq & 1) << 5);
#pragma unroll
        for (int nf = 0; nf < 2; ++nf) {
            const int gc = ccol + (nf << 7);
            const float bv = bias[gc];
#pragma unroll
            for (int reg = 0; reg < 16; ++reg) {
                const int gr = rbase + (reg & 3) + ((reg >> 2) << 3);
                const float v = acc[mq][nf][reg] + bv;
                if (OUT_F16)
                    ((_Float16*)Cout)[(size_t)gr * N + gc] = (_Float16)v;
                else
                    ((float*)Cout)[(size_t)gr * N + gc] = v;
            }
        }
    }
    (void)M;
}

// ---------------------------------------------------------------------------
// Fused rope + attention. One block per (b,h). qkv: (4096, 12288) f16,
// q at col h*64+d, k at 4096+h*64+d, v at 8192+h*64+d. out: (4096,4096) f16.
// RoPE quirk: theta = b * 10000^(-(s*32 + d/2)/2048).
// ---------------------------------------------------------------------------
__global__ __launch_bounds__(256) void attn_kernel(
    const _Float16* __restrict__ qkv, _Float16* __restrict__ out)
{
    __shared__ __align__(16) _Float16 qs[64][72];
    __shared__ __align__(16) _Float16 ks[64][72];
    __shared__ __align__(16) _Float16 vt[64][72];   // vt[d][s_k]
    __shared__ __align__(16) _Float16 ps[4][16][72];

    const int tid  = threadIdx.x;
    const int bb   = blockIdx.x >> 6;   // batch
    const int hh   = blockIdx.x & 63;   // head
    const int wave = tid >> 6;
    const int lane = tid & 63;
    const int r  = tid >> 2;            // row s, 0..63
    const int cb = (tid & 3) * 8;       // col base within 32-chunk
    const float fb = (float)bb;

    const _Float16* grow = qkv + (size_t)(bb * 64 + r) * 12288 + hh * 64;

#pragma unroll
    for (int u = 0; u < 2; u++) {
        const int c8 = cb + u * 32;     // contiguous 32-col chunks per 4-lane group
        half8 q8 = *(const half8*)(grow + c8);
        half8 k8 = *(const half8*)(grow + 4096 + c8);
        half8 v8 = *(const half8*)(grow + 8192 + c8);
#pragma unroll
        for (int p = 0; p < 4; p++) {
            const int m = r * 32 + (c8 >> 1) + p;
            const float theta = fb * exp2f((float)m * NEG_LOG2_10000_OVER_2048);
            float sn, cs;
            __sincosf(theta, &sn, &cs);
            const float qe = (float)q8[2 * p], qo = (float)q8[2 * p + 1];
            q8[2 * p]     = (_Float16)(qe * cs - qo * sn);
            q8[2 * p + 1] = (_Float16)(qe * sn + qo * cs);
            const float ke = (float)k8[2 * p], ko = (float)k8[2 * p + 1];
            k8[2 * p]     = (_Float16)(ke * cs - ko * sn);
            k8[2 * p + 1] = (_Float16)(ke * sn + ko * cs);
        }
        *(half8*)&qs[r][c8] = q8;
        *(half8*)&ks[r][c8] = k8;
#pragma unroll
        for (int j = 0; j < 8; j++) vt[c8 + j][r] = v8[j];
    }
    __syncthreads();

    const int fr = lane & 15;
    const int fc = (lane >> 4) * 8;

    // scores: wave handles rows sq in [wave*16, wave*16+16), all 64 cols
    floatx4 sa[4];
#pragma unroll
    for (int t = 0; t < 4; t++) sa[t] = (floatx4){0.f, 0.f, 0.f, 0.f};
    half8 a0 = *(const half8*)&qs[wave * 16 + fr][fc];
    half8 a1 = *(const half8*)&qs[wave * 16 + fr][fc + 32];
#pragma unroll
    for (int t = 0; t < 4; t++) {
        half8 kb0 = *(const half8*)&ks[t * 16 + fr][fc];
        half8 kb1 = *(const half8*)&ks[t * 16 + fr][fc + 32];
        sa[t] = __builtin_amdgcn_mfma_f32_16x16x32_f16(a0, kb0, sa[t], 0, 0, 0);
        sa[t] = __builtin_amdgcn_mfma_f32_16x16x32_f16(a1, kb1, sa[t], 0, 0, 0);
    }

    // softmax over 64 cols; row = wave*16 + (lane>>4)*4 + i
#pragma unroll
    for (int i = 0; i < 4; i++) {
        float mx = -1e30f;
#pragma unroll
        for (int t = 0; t < 4; t++) mx = fmaxf(mx, sa[t][i]);
#pragma unroll
        for (int d = 1; d < 16; d <<= 1) mx = fmaxf(mx, __shfl_xor(mx, d));
        float sum = 0.f;
        float pv[4];
#pragma unroll
        for (int t = 0; t < 4; t++) {
            const float e = __expf((sa[t][i] - mx) * 0.125f);
            pv[t] = e;
            sum += e;
        }
#pragma unroll
        for (int d = 1; d < 16; d <<= 1) sum += __shfl_xor(sum, d);
        const float inv = 1.0f / sum;
        const int prow = ((lane >> 4) << 2) + i;
#pragma unroll
        for (int t = 0; t < 4; t++)
            ps[wave][prow][t * 16 + fr] = (_Float16)(pv[t] * inv);
    }
    // ps[wave] is written+read only by this wave; LDS ops are wave-ordered.

    // PV: O[sq][d] = sum_sk P[sq][sk] * V[sk][d]
    half8 pa0 = *(const half8*)&ps[wave][fr][fc];
    half8 pa1 = *(const half8*)&ps[wave][fr][fc + 32];
    floatx4 oa[4];
#pragma unroll
    for (int t = 0; t < 4; t++) oa[t] = (floatx4){0.f, 0.f, 0.f, 0.f};
#pragma unroll
    for (int t = 0; t < 4; t++) {
        half8 vb0 = *(const half8*)&vt[t * 16 + fr][fc];
        half8 vb1 = *(const half8*)&vt[t * 16 + fr][fc + 32];
        oa[t] = __builtin_amdgcn_mfma_f32_16x16x32_f16(pa0, vb0, oa[t], 0, 0, 0);
        oa[t] = __builtin_amdgcn_mfma_f32_16x16x32_f16(pa1, vb1, oa[t], 0, 0, 0);
    }

    _Float16* obase = out + (size_t)(bb * 64) * 4096 + hh * 64;
#pragma unroll
    for (int t = 0; t < 4; t++)
#pragma unroll
        for (int i = 0; i < 4; i++) {
            const int sq = wave * 16 + ((lane >> 4) << 2) + i;
            obase[(size_t)sq * 4096 + t * 16 + fr] = (_Float16)oa[t][i];
        }
}

// ---------------------------------------------------------------------------
// launcher
// ---------------------------------------------------------------------------
extern "C" void kernel_launch(void* const* d_in, const int* in_sizes, int n_in,
                              void* d_out, int out_size, void* d_ws, size_t ws_size,
                              hipStream_t stream)
{
    const float* x  = (const float*)d_in[0];
    const float* wq = (const float*)d_in[1];
    const float* bq = (const float*)d_in[2];
    const float* wk = (const float*)d_in[3];
    const float* bk = (const float*)d_in[4];
    const float* wv = (const float*)d_in[5];
    const float* bv = (const float*)d_in[6];
    const float* wo = (const float*)d_in[7];
    const float* bo = (const float*)d_in[8];

    char* ws = (char*)d_ws;
    _Float16* xh      = (_Float16*)(ws);                          // 32 MiB
    _Float16* wcat    = (_Float16*)(ws + 33554432);               // 96 MiB (wq|wk|wv)
    _Float16* woh     = (_Float16*)(ws + 134217728);              // 32 MiB
    _Float16* qkv     = (_Float16*)(ws + 167772160);              // 96 MiB
    _Float16* attnbuf = (_Float16*)(ws + 268435456);              // 32 MiB
    float*    biascat = (float*)(ws + 301989888);                 // 48 KiB

    cast5_kernel<<<dim3(1024, 5), dim3(256), 0, stream>>>(
        x, wq, wk, wv, wo, xh, wcat, woh);
    biascat_kernel<<<dim3(16), dim3(256), 0, stream>>>(bq, bk, bv, biascat);

    // QKV projection: C(4096,12288) = xh @ wcat^T + biascat
    gemm_nt_256<1><<<dim3(768), dim3(512), 0, stream>>>(
        xh, wcat, biascat, qkv, 4096, 12288, 4096);

    // fused rope + attention
    attn_kernel<<<dim3(4096), dim3(256), 0, stream>>>(qkv, attnbuf);

    // output projection: d_out(4096,4096) fp32 = attn @ wo^T + bo
    gemm_nt_256<0><<<dim3(256), dim3(512), 0, stream>>>(
        attnbuf, woh, bo, d_out, 4096, 4096, 4096);
}